// Round 4
// baseline (121.653 us; speedup 1.0000x reference)
//
#include <hip/hip_runtime.h>
#include <hip/hip_bf16.h>
#include <math.h>

// Problem constants
#define BATCH 8
#define HH 512
#define WW 512
#define COUT 256
#define NPTS 11          // 5 + 6
#define CASC 3
#define FH 128           // conv output spatial
#define FW 128
#define KT 49            // 7x7 taps
#define NBK (BATCH*NPTS) // 88
#define NSPLIT 128       // argmax row-splits per image (fused: one block each)
#define OROWS (HH/NSPLIT) // 4 output rows per split
#define MAXR 3           // max feature rows a split touches (span<=1 +1 +1)

// ws layout (floats)
// fold: [0..538]   scoreW in [t][k] layout (t*11+k)
//       [539..549] scoreB[k]
//       [550..843] shiftW[i*2+j][t] (49 each)
//       [844..849] shiftB
#define FOLD_OFF   0
#define PVAL_OFF   1024                      // 88*128 = 11264 floats
#define PIDX_OFF   (PVAL_OFF + NBK*NSPLIT)   // 11264 ints

#define STEPC (127.0f/511.0f)

// ---------------------------------------------------------------------------
// Kernel 1: fold weights. One wave per output (850 outputs = 17 rows x 50
// cols; col 49 = bias). 213 blocks x 256 threads (4 waves/block).
// NOTE: do NOT fuse downstream via atomics (45 us on multi-XCD); keep the
// lane-strided sum + shfl reduction order (absmax=0.0 verified against it).
__global__ __launch_bounds__(256) void fold_kernel(
    const float* __restrict__ bw, const float* __restrict__ bb,
    const float* __restrict__ fcw, const float* __restrict__ fcb,
    const float* __restrict__ hw, const float* __restrict__ hb,
    float* __restrict__ fold) {
  int id = blockIdx.x*4 + (threadIdx.x >> 6);   // 0..851
  if (id >= 850) return;
  int row = id / 50, t = id % 50;
  int lane = threadIdx.x & 63;
  float acc = 0.f;
  for (int c = lane; c < COUT; c += 64) {
    float coef;
    if (row < NPTS) {
      coef = fcw[row*COUT + c];
    } else {
      int r = row - NPTS;
      coef = hw[(r >> 1)*(COUT*2) + c*2 + (r & 1)];
    }
    float wsum;
    if (t < KT) {
      const float* p = bw + c*(3*KT) + t;
      wsum = p[0] + p[KT] + p[2*KT];
    } else {
      wsum = bb[c];
    }
    acc += coef * wsum;
  }
  #pragma unroll
  for (int off = 32; off > 0; off >>= 1) acc += __shfl_down(acc, off);
  if (lane == 0) {
    if (t == KT) acc += (row < NPTS) ? fcb[row] : hb[row - NPTS];
    if (row < NPTS) {
      if (t < KT) fold[t*NPTS + row] = acc;                   // [t][k] layout
      else        fold[NPTS*KT + row] = acc;                  // scoreB at 539..549
    } else {
      int r = row - NPTS;
      if (t < KT) fold[550 + r*KT + t] = acc;                 // shiftW
      else        fold[844 + r] = acc;                        // shiftB
    }
  }
}

// ---------------------------------------------------------------------------
// Kernel 2 (R8): per-split conv + candidate argmax.
// Occupancy: 1024 blocks (4/CU). XCD swizzle b=blk&7 keeps each image on
// one XCD's L2 for the 3x row re-reads.
// R8 change: conv image loads vectorized — 2 aligned float4 per kernel row
// ([4x-4..4x-1] and [4x..4x+3]) instead of 49 scalar stride-4 loads.
// Taps come from vector components; OOB rows / x==0 left edge substitute
// 0.5f so xv=0 and fmaf(w,0,acc)==acc — the fmaf CHAIN VALUES are
// identical to the verbatim absmax=0.0 kernel at every step (right edge
// provably never OOB: ix=505+kw<=511). Candidate scan unchanged.
__global__ __launch_bounds__(256) void score_argmax_kernel(
    const float* __restrict__ img, const float* __restrict__ fold,
    float* __restrict__ pval, int* __restrict__ pidx) {
  __shared__ __align__(16) float s[NPTS*MAXR*FW];   // 11*3*128*4 = 16896 B
  __shared__ float wvv[NPTS*4];
  __shared__ int   wvi[NPTS*4];
  int b = blockIdx.x & 7;     // image -> XCD (dispatch round-robins % 8)
  int q = blockIdx.x >> 3;    // split 0..127

  int oyb = q*OROWS;
  int ybase = (int)((float)oyb * STEPC);
  int ylast = (int)((float)(oyb + OROWS - 1) * STEPC);
  int yend  = min(ylast + 1, FH - 1);
  int rows  = yend - ybase + 1;              // <= 3
  const float* im = img + (size_t)b * (HH*WW);

  // --- conv phase: rows x 128 pixels, 11 channels each, into LDS ---
  for (int p = threadIdx.x; p < rows*FW; p += 256) {
    int ry = p >> 7;                 // 0..rows-1
    int x  = p & 127;
    int y  = ybase + ry;
    float acc[NPTS];
    #pragma unroll
    for (int k = 0; k < NPTS; ++k) acc[k] = fold[NPTS*KT + k];   // uniform -> s_load
    int iy0 = y*4 - 3;
    const float4 h4 = {0.5f, 0.5f, 0.5f, 0.5f};
    #pragma unroll
    for (int kh = 0; kh < 7; ++kh) {
      int iy = iy0 + kh;
      float4 va, vb;
      if (iy < 0 || iy >= HH) { va = h4; vb = h4; }
      else {
        const float* rp = im + iy*WW + x*4;        // 16B-aligned
        vb = *(const float4*)rp;
        va = (x > 0) ? *(const float4*)(rp - 4) : h4;
      }
      int tb = kh*7;
      // taps kw=0..2 from va.y/.z/.w (ix=4x-3..4x-1), kw=3..6 from vb
      {
        float xv = va.y - 0.5f;
        #pragma unroll
        for (int k = 0; k < NPTS; ++k) acc[k] = fmaf(fold[(tb+0)*NPTS + k], xv, acc[k]);
      }
      {
        float xv = va.z - 0.5f;
        #pragma unroll
        for (int k = 0; k < NPTS; ++k) acc[k] = fmaf(fold[(tb+1)*NPTS + k], xv, acc[k]);
      }
      {
        float xv = va.w - 0.5f;
        #pragma unroll
        for (int k = 0; k < NPTS; ++k) acc[k] = fmaf(fold[(tb+2)*NPTS + k], xv, acc[k]);
      }
      {
        float xv = vb.x - 0.5f;
        #pragma unroll
        for (int k = 0; k < NPTS; ++k) acc[k] = fmaf(fold[(tb+3)*NPTS + k], xv, acc[k]);
      }
      {
        float xv = vb.y - 0.5f;
        #pragma unroll
        for (int k = 0; k < NPTS; ++k) acc[k] = fmaf(fold[(tb+4)*NPTS + k], xv, acc[k]);
      }
      {
        float xv = vb.z - 0.5f;
        #pragma unroll
        for (int k = 0; k < NPTS; ++k) acc[k] = fmaf(fold[(tb+5)*NPTS + k], xv, acc[k]);
      }
      {
        float xv = vb.w - 0.5f;
        #pragma unroll
        for (int k = 0; k < NPTS; ++k) acc[k] = fmaf(fold[(tb+6)*NPTS + k], xv, acc[k]);
      }
    }
    #pragma unroll
    for (int k = 0; k < NPTS; ++k) s[(k*MAXR + ry)*FW + x] = acc[k];
  }
  __syncthreads();

  // --- argmax phase: verbatim candidate logic ---
  // per-thread candidate column: thread t owns x-bucket t>>1, (t&1 ? last :
  // first) sampled col of that bucket. kb=127 is the singleton {511} (dup ok).
  int t = threadIdx.x;
  int kb = t >> 1;
  int cf = (kb*511 + 126)/127;
  int cl = (kb < 127) ? ((kb + 1)*511 + 126)/127 - 1 : 511;
  int ox = (t & 1) ? cl : cf;
  float tx = (float)ox * STEPC;
  int xa0 = (int)tx;
  float wx = tx - (float)xa0;
  int xa1 = min(xa0 + 1, FW - 1);
  float omwx = 1.f - wx;
  int wave = threadIdx.x >> 6;
  int lane = threadIdx.x & 63;

  #pragma unroll
  for (int ch = 0; ch < NPTS; ++ch) {
    float best = -3.4028235e38f;
    int bidx = 0x7fffffff;
    for (int k = ybase; k <= ylast; ++k) {   // y-buckets intersecting split
      int y1 = min(k + 1, FH - 1);
      const float* r0 = s + (ch*MAXR + (k  - ybase))*FW;
      const float* r1 = s + (ch*MAXR + (y1 - ybase))*FW;
      float A = r0[xa0], B = r1[xa0], C = r0[xa1], D = r1[xa1];
      int rf = (k*511 + 126)/127;                              // first row of bucket
      int rl = (k < 127) ? ((k + 1)*511 + 126)/127 - 1 : 511;  // last row
      if (rf >= oyb && rf < oyb + OROWS) {
        float ty = (float)rf * STEPC;
        int y0i = (int)ty;
        float wy = ty - (float)y0i;
        float omwy = 1.f - wy;
        float top0 = A*omwy + B*wy;
        float top1 = C*omwy + D*wy;
        float v = top0*omwx + top1*wx;
        if (v > best) { best = v; bidx = rf*512 + ox; }
      }
      if (rl != rf && rl >= oyb && rl < oyb + OROWS) {
        float ty = (float)rl * STEPC;
        int y0i = (int)ty;
        float wy = ty - (float)y0i;
        float omwy = 1.f - wy;
        float top0 = A*omwy + B*wy;
        float top1 = C*omwy + D*wy;
        float v = top0*omwx + top1*wx;
        if (v > best) { best = v; bidx = rl*512 + ox; }
      }
    }
    // intra-wave reduce (value desc, index asc tie-break) — no barriers
    #pragma unroll
    for (int off = 32; off > 0; off >>= 1) {
      float ov = __shfl_down(best, off);
      int   oi = __shfl_down(bidx, off);
      if (ov > best || (ov == best && oi < bidx)) { best = ov; bidx = oi; }
    }
    if (lane == 0) { wvv[ch*4 + wave] = best; wvi[ch*4 + wave] = bidx; }
  }
  __syncthreads();
  if (threadIdx.x < NPTS) {
    int ch = threadIdx.x;
    float best = wvv[ch*4]; int bidx = wvi[ch*4];
    #pragma unroll
    for (int w = 1; w < 4; ++w) {
      float ov = wvv[ch*4 + w]; int oi = wvi[ch*4 + w];
      if (ov > best || (ov == best && oi < bidx)) { best = ov; bidx = oi; }
    }
    int bk = b*NPTS + ch;
    pval[bk*NSPLIT + q] = best;
    pidx[bk*NSPLIT + q] = bidx;
  }
}

// ---------------------------------------------------------------------------
// Kernel 3 (R8): one block per (b,k) point. R7 post-mortem: lane-0-only
// 3x49 branchy scattered loads on L2/L3-flushed (poison-filled) memory =
// ~19 us of serial ~900cy HBM latency. Fix: lane t<49 loads tap t in ONE
// parallel wave-load; all lanes then replay the t=0..48 serial fmaf chain
// via __shfl(xv,t) — OOB taps carry xv=0 and fmaf(w,0,acc)==acc (finite),
// so every chain intermediate equals the verbatim serial version. Merge
// comparator is an associative semilattice max -> wave-reduce bit-identical.
__global__ __launch_bounds__(64) void cascade_kernel(
    const float* __restrict__ img, const float* __restrict__ fold,
    const float* __restrict__ pval, const int* __restrict__ pidx,
    float* __restrict__ out) {
  int p = blockIdx.x;          // bk index = b*11 + k
  int lane = threadIdx.x;      // 0..63
  float best = pval[p*NSPLIT + lane];
  int   bidx = pidx[p*NSPLIT + lane];
  {
    float v1 = pval[p*NSPLIT + 64 + lane];
    int   i1 = pidx[p*NSPLIT + 64 + lane];
    if (v1 > best || (v1 == best && i1 < bidx)) { best = v1; bidx = i1; }
  }
  #pragma unroll
  for (int off = 32; off > 0; off >>= 1) {
    float ov = __shfl_down(best, off);
    int   oi = __shfl_down(bidx, off);
    if (ov > best || (ov == best && oi < bidx)) { best = ov; bidx = oi; }
  }
  bidx = __shfl(bidx, 0);      // broadcast winner to all lanes

  float cx = (float)(bidx & 511);
  float cy = (float)(bidx >> 9);
  int b = p / NPTS;
  const float* im = img + (size_t)b * (HH*WW);
  int kh = lane / 7, kw = lane % 7;     // tap owned by this lane (lane<49)
  for (int i = 0; i < CASC; ++i) {
    // hi from y-coord, wi from x-coord; jnp.round = RNE = rintf
    float ry = rintf(cy * 0.25f), rx = rintf(cx * 0.25f);
    int hi = (int)fminf(fmaxf(ry, 0.f), (float)(FH - 1));
    int wi = (int)fminf(fmaxf(rx, 0.f), (float)(FW - 1));
    int iy0 = hi*4 - 3, ix0 = wi*4 - 3;
    float xv = 0.f;
    if (lane < KT) {
      int iy = iy0 + kh, ix = ix0 + kw;
      if (iy >= 0 && iy < HH && ix >= 0 && ix < WW)
        xv = im[iy*WW + ix] - 0.5f;
    }
    float s0 = fold[844 + i*2 + 0];
    float s1 = fold[844 + i*2 + 1];
    #pragma unroll
    for (int t = 0; t < KT; ++t) {
      float xvt = __shfl(xv, t);
      s0 = fmaf(fold[550 + (i*2 + 0)*KT + t], xvt, s0);
      s1 = fmaf(fold[550 + (i*2 + 1)*KT + t], xvt, s1);
    }
    cx += s0;     // uniform across lanes (same shfl data, same arithmetic)
    cy += s1;
  }
  if (lane == 0) {
    out[p*2 + 0] = cx;
    out[p*2 + 1] = cy;
  }
}

// ---------------------------------------------------------------------------
extern "C" void kernel_launch(void* const* d_in, const int* in_sizes, int n_in,
                              void* d_out, int out_size, void* d_ws, size_t ws_size,
                              hipStream_t stream) {
  const float* img = (const float*)d_in[0];   // (8,1,512,512)
  const float* bw  = (const float*)d_in[1];   // (256,3,7,7)
  const float* bb  = (const float*)d_in[2];   // (256,)
  const float* fcw = (const float*)d_in[3];   // (11,256)
  const float* fcb = (const float*)d_in[4];   // (11,)
  const float* hw  = (const float*)d_in[5];   // (3,256,2)
  const float* hb  = (const float*)d_in[6];   // (3,2)
  float* out = (float*)d_out;                 // (8,11,2) f32

  float* ws     = (float*)d_ws;
  float* fold   = ws + FOLD_OFF;
  float* pval   = ws + PVAL_OFF;
  int*   pidx   = (int*)(ws + PIDX_OFF);

  fold_kernel<<<213, 256, 0, stream>>>(bw, bb, fcw, fcb, hw, hb, fold);
  score_argmax_kernel<<<BATCH*NSPLIT, 256, 0, stream>>>(img, fold, pval, pidx);
  cascade_kernel<<<NBK, 64, 0, stream>>>(img, fold, pval, pidx, out);
}

// Round 5
// 109.017 us; speedup vs baseline: 1.1159x; 1.1159x over previous
//
#include <hip/hip_runtime.h>
#include <hip/hip_bf16.h>
#include <math.h>

// Problem constants
#define BATCH 8
#define HH 512
#define WW 512
#define COUT 256
#define NPTS 11          // 5 + 6
#define CASC 3
#define FH 128           // conv output spatial
#define FW 128
#define KT 49            // 7x7 taps
#define NBK (BATCH*NPTS) // 88
#define NSPLIT 128       // argmax row-splits per image (fused: one block each)
#define OROWS (HH/NSPLIT) // 4 output rows per split
#define MAXR 3           // max feature rows a split touches (span<=1 +1 +1)

// ws layout (floats)
// fold: [0..538]   scoreW in [t][k] layout (t*11+k)
//       [539..549] scoreB[k]
//       [550..843] shiftW[i*2+j][t] (49 each)
//       [844..849] shiftB
#define FOLD_OFF   0
#define PVAL_OFF   1024                      // 88*128 = 11264 floats
#define PIDX_OFF   (PVAL_OFF + NBK*NSPLIT)   // 11264 ints

#define STEPC (127.0f/511.0f)

// ---------------------------------------------------------------------------
// Kernel 1: fold weights. One wave per output (850 outputs = 17 rows x 50
// cols; col 49 = bias). 213 blocks x 256 threads (4 waves/block).
// NOTE: do NOT fuse downstream via atomics (45 us on multi-XCD); keep the
// lane-strided sum + shfl reduction order (absmax=0.0 verified against it).
__global__ __launch_bounds__(256) void fold_kernel(
    const float* __restrict__ bw, const float* __restrict__ bb,
    const float* __restrict__ fcw, const float* __restrict__ fcb,
    const float* __restrict__ hw, const float* __restrict__ hb,
    float* __restrict__ fold) {
  int id = blockIdx.x*4 + (threadIdx.x >> 6);   // 0..851
  if (id >= 850) return;
  int row = id / 50, t = id % 50;
  int lane = threadIdx.x & 63;
  float acc = 0.f;
  for (int c = lane; c < COUT; c += 64) {
    float coef;
    if (row < NPTS) {
      coef = fcw[row*COUT + c];
    } else {
      int r = row - NPTS;
      coef = hw[(r >> 1)*(COUT*2) + c*2 + (r & 1)];
    }
    float wsum;
    if (t < KT) {
      const float* p = bw + c*(3*KT) + t;
      wsum = p[0] + p[KT] + p[2*KT];
    } else {
      wsum = bb[c];
    }
    acc += coef * wsum;
  }
  #pragma unroll
  for (int off = 32; off > 0; off >>= 1) acc += __shfl_down(acc, off);
  if (lane == 0) {
    if (t == KT) acc += (row < NPTS) ? fcb[row] : hb[row - NPTS];
    if (row < NPTS) {
      if (t < KT) fold[t*NPTS + row] = acc;                   // [t][k] layout
      else        fold[NPTS*KT + row] = acc;                  // scoreB at 539..549
    } else {
      int r = row - NPTS;
      if (t < KT) fold[550 + r*KT + t] = acc;                 // shiftW
      else        fold[844 + r] = acc;                        // shiftB
    }
  }
}

// ---------------------------------------------------------------------------
// Kernel 2 (R9 = R6 revert): per-split conv + candidate argmax.
// R8 post-mortem: the "vectorized" conv (2x float4/row + conditional left
// edge) REGRESSED 14 -> 33 us timed (60 us rocprof; VALUBusy 31% = 6x the
// FMA floor). The scalar stride-4 tap loads are already wave-coalesced
// (consecutive lanes 16B apart), reuse L1 lines across 4 taps, and give
// the scheduler 49 independent loads to pipeline against the fmaf chains.
// DO NOT re-vectorize this conv without a within-run A/B.
// Occupancy: 1024 blocks (4/CU). XCD swizzle b=blk&7 keeps each image on
// one XCD's L2 for the 3x row re-reads. Conv per-pixel arithmetic and
// candidate scan are VERBATIM from the absmax=0.0 kernels.
__global__ __launch_bounds__(256) void score_argmax_kernel(
    const float* __restrict__ img, const float* __restrict__ fold,
    float* __restrict__ pval, int* __restrict__ pidx) {
  __shared__ __align__(16) float s[NPTS*MAXR*FW];   // 11*3*128*4 = 16896 B
  __shared__ float wvv[NPTS*4];
  __shared__ int   wvi[NPTS*4];
  int b = blockIdx.x & 7;     // image -> XCD (dispatch round-robins % 8)
  int q = blockIdx.x >> 3;    // split 0..127

  int oyb = q*OROWS;
  int ybase = (int)((float)oyb * STEPC);
  int ylast = (int)((float)(oyb + OROWS - 1) * STEPC);
  int yend  = min(ylast + 1, FH - 1);
  int rows  = yend - ybase + 1;              // <= 3
  const float* im = img + (size_t)b * (HH*WW);

  // --- conv phase: rows x 128 pixels, 11 channels each, into LDS ---
  for (int p = threadIdx.x; p < rows*FW; p += 256) {
    int ry = p >> 7;                 // 0..rows-1
    int x  = p & 127;
    int y  = ybase + ry;
    float acc[NPTS];
    #pragma unroll
    for (int k = 0; k < NPTS; ++k) acc[k] = fold[NPTS*KT + k];   // uniform -> s_load
    int iy0 = y*4 - 3, ix0 = x*4 - 3;
    #pragma unroll
    for (int kh = 0; kh < 7; ++kh) {
      int iy = iy0 + kh;
      if (iy < 0 || iy >= HH) continue;
      #pragma unroll
      for (int kw = 0; kw < 7; ++kw) {
        int ix = ix0 + kw;
        if (ix < 0 || ix >= WW) continue;
        float xv = im[iy*WW + ix] - 0.5f;
        int t = kh*7 + kw;
        #pragma unroll
        for (int k = 0; k < NPTS; ++k) acc[k] = fmaf(fold[t*NPTS + k], xv, acc[k]);
      }
    }
    #pragma unroll
    for (int k = 0; k < NPTS; ++k) s[(k*MAXR + ry)*FW + x] = acc[k];
  }
  __syncthreads();

  // --- argmax phase: verbatim candidate logic ---
  // per-thread candidate column: thread t owns x-bucket t>>1, (t&1 ? last :
  // first) sampled col of that bucket. kb=127 is the singleton {511} (dup ok).
  int t = threadIdx.x;
  int kb = t >> 1;
  int cf = (kb*511 + 126)/127;
  int cl = (kb < 127) ? ((kb + 1)*511 + 126)/127 - 1 : 511;
  int ox = (t & 1) ? cl : cf;
  float tx = (float)ox * STEPC;
  int xa0 = (int)tx;
  float wx = tx - (float)xa0;
  int xa1 = min(xa0 + 1, FW - 1);
  float omwx = 1.f - wx;
  int wave = threadIdx.x >> 6;
  int lane = threadIdx.x & 63;

  #pragma unroll
  for (int ch = 0; ch < NPTS; ++ch) {
    float best = -3.4028235e38f;
    int bidx = 0x7fffffff;
    for (int k = ybase; k <= ylast; ++k) {   // y-buckets intersecting split
      int y1 = min(k + 1, FH - 1);
      const float* r0 = s + (ch*MAXR + (k  - ybase))*FW;
      const float* r1 = s + (ch*MAXR + (y1 - ybase))*FW;
      float A = r0[xa0], B = r1[xa0], C = r0[xa1], D = r1[xa1];
      int rf = (k*511 + 126)/127;                              // first row of bucket
      int rl = (k < 127) ? ((k + 1)*511 + 126)/127 - 1 : 511;  // last row
      if (rf >= oyb && rf < oyb + OROWS) {
        float ty = (float)rf * STEPC;
        int y0i = (int)ty;
        float wy = ty - (float)y0i;
        float omwy = 1.f - wy;
        float top0 = A*omwy + B*wy;
        float top1 = C*omwy + D*wy;
        float v = top0*omwx + top1*wx;
        if (v > best) { best = v; bidx = rf*512 + ox; }
      }
      if (rl != rf && rl >= oyb && rl < oyb + OROWS) {
        float ty = (float)rl * STEPC;
        int y0i = (int)ty;
        float wy = ty - (float)y0i;
        float omwy = 1.f - wy;
        float top0 = A*omwy + B*wy;
        float top1 = C*omwy + D*wy;
        float v = top0*omwx + top1*wx;
        if (v > best) { best = v; bidx = rl*512 + ox; }
      }
    }
    // intra-wave reduce (value desc, index asc tie-break) — no barriers
    #pragma unroll
    for (int off = 32; off > 0; off >>= 1) {
      float ov = __shfl_down(best, off);
      int   oi = __shfl_down(bidx, off);
      if (ov > best || (ov == best && oi < bidx)) { best = ov; bidx = oi; }
    }
    if (lane == 0) { wvv[ch*4 + wave] = best; wvi[ch*4 + wave] = bidx; }
  }
  __syncthreads();
  if (threadIdx.x < NPTS) {
    int ch = threadIdx.x;
    float best = wvv[ch*4]; int bidx = wvi[ch*4];
    #pragma unroll
    for (int w = 1; w < 4; ++w) {
      float ov = wvv[ch*4 + w]; int oi = wvi[ch*4 + w];
      if (ov > best || (ov == best && oi < bidx)) { best = ov; bidx = oi; }
    }
    int bk = b*NPTS + ch;
    pval[bk*NSPLIT + q] = best;
    pidx[bk*NSPLIT + q] = bidx;
  }
}

// ---------------------------------------------------------------------------
// Kernel 3 (R8, kept): one block per (b,k) point. Lane t<49 loads tap t in
// ONE parallel wave-load (was: lane-0-only serial loads = ~19 us exposed
// HBM latency on poison-flushed caches); all lanes replay the t=0..48
// serial fmaf chain via __shfl(xv,t) — OOB taps carry xv=0 and
// fmaf(w,0,acc)==acc (finite), so every chain intermediate equals the
// verbatim serial version. Merge comparator is an associative semilattice
// max -> wave-reduce gives the bit-identical winner.
__global__ __launch_bounds__(64) void cascade_kernel(
    const float* __restrict__ img, const float* __restrict__ fold,
    const float* __restrict__ pval, const int* __restrict__ pidx,
    float* __restrict__ out) {
  int p = blockIdx.x;          // bk index = b*11 + k
  int lane = threadIdx.x;      // 0..63
  float best = pval[p*NSPLIT + lane];
  int   bidx = pidx[p*NSPLIT + lane];
  {
    float v1 = pval[p*NSPLIT + 64 + lane];
    int   i1 = pidx[p*NSPLIT + 64 + lane];
    if (v1 > best || (v1 == best && i1 < bidx)) { best = v1; bidx = i1; }
  }
  #pragma unroll
  for (int off = 32; off > 0; off >>= 1) {
    float ov = __shfl_down(best, off);
    int   oi = __shfl_down(bidx, off);
    if (ov > best || (ov == best && oi < bidx)) { best = ov; bidx = oi; }
  }
  bidx = __shfl(bidx, 0);      // broadcast winner to all lanes

  float cx = (float)(bidx & 511);
  float cy = (float)(bidx >> 9);
  int b = p / NPTS;
  const float* im = img + (size_t)b * (HH*WW);
  int kh = lane / 7, kw = lane % 7;     // tap owned by this lane (lane<49)
  for (int i = 0; i < CASC; ++i) {
    // hi from y-coord, wi from x-coord; jnp.round = RNE = rintf
    float ry = rintf(cy * 0.25f), rx = rintf(cx * 0.25f);
    int hi = (int)fminf(fmaxf(ry, 0.f), (float)(FH - 1));
    int wi = (int)fminf(fmaxf(rx, 0.f), (float)(FW - 1));
    int iy0 = hi*4 - 3, ix0 = wi*4 - 3;
    float xv = 0.f;
    if (lane < KT) {
      int iy = iy0 + kh, ix = ix0 + kw;
      if (iy >= 0 && iy < HH && ix >= 0 && ix < WW)
        xv = im[iy*WW + ix] - 0.5f;
    }
    float s0 = fold[844 + i*2 + 0];
    float s1 = fold[844 + i*2 + 1];
    #pragma unroll
    for (int t = 0; t < KT; ++t) {
      float xvt = __shfl(xv, t);
      s0 = fmaf(fold[550 + (i*2 + 0)*KT + t], xvt, s0);
      s1 = fmaf(fold[550 + (i*2 + 1)*KT + t], xvt, s1);
    }
    cx += s0;     // uniform across lanes (same shfl data, same arithmetic)
    cy += s1;
  }
  if (lane == 0) {
    out[p*2 + 0] = cx;
    out[p*2 + 1] = cy;
  }
}

// ---------------------------------------------------------------------------
extern "C" void kernel_launch(void* const* d_in, const int* in_sizes, int n_in,
                              void* d_out, int out_size, void* d_ws, size_t ws_size,
                              hipStream_t stream) {
  const float* img = (const float*)d_in[0];   // (8,1,512,512)
  const float* bw  = (const float*)d_in[1];   // (256,3,7,7)
  const float* bb  = (const float*)d_in[2];   // (256,)
  const float* fcw = (const float*)d_in[3];   // (11,256)
  const float* fcb = (const float*)d_in[4];   // (11,)
  const float* hw  = (const float*)d_in[5];   // (3,256,2)
  const float* hb  = (const float*)d_in[6];   // (3,2)
  float* out = (float*)d_out;                 // (8,11,2) f32

  float* ws     = (float*)d_ws;
  float* fold   = ws + FOLD_OFF;
  float* pval   = ws + PVAL_OFF;
  int*   pidx   = (int*)(ws + PIDX_OFF);

  fold_kernel<<<213, 256, 0, stream>>>(bw, bb, fcw, fcb, hw, hb, fold);
  score_argmax_kernel<<<BATCH*NSPLIT, 256, 0, stream>>>(img, fold, pval, pidx);
  cascade_kernel<<<NBK, 64, 0, stream>>>(img, fold, pval, pidx, out);
}

// Round 6
// 97.567 us; speedup vs baseline: 1.2469x; 1.1174x over previous
//
#include <hip/hip_runtime.h>
#include <hip/hip_bf16.h>
#include <math.h>

// Problem constants
#define BATCH 8
#define HH 512
#define WW 512
#define COUT 256
#define NPTS 11          // 5 + 6
#define CASC 3
#define FH 128           // conv output spatial
#define FW 128
#define KT 49            // 7x7 taps
#define NBK (BATCH*NPTS) // 88
#define NSPLIT 128       // partials per (b,k) point = feature cells 0..127
#define STEPC (127.0f/511.0f)

// ws layout (floats)
// fold: [0..538]   scoreW in [t][k] layout (t*11+k)
//       [539..549] scoreB[k]
//       [550..843] shiftW[i*2+j][t] (49 each)
//       [844..849] shiftB
#define FOLD_OFF   0
#define PVAL_OFF   1024                      // 88*128 = 11264 floats
#define PIDX_OFF   (PVAL_OFF + NBK*NSPLIT)   // 11264 ints

// ---------------------------------------------------------------------------
// Kernel 1: fold weights. One wave per output (850 outputs = 17 rows x 50
// cols; col 49 = bias). 213 blocks x 256 threads (4 waves/block).
// NOTE: do NOT fuse downstream via atomics (45 us on multi-XCD); keep the
// lane-strided sum + shfl reduction order (absmax=0.0 verified against it).
__global__ __launch_bounds__(256) void fold_kernel(
    const float* __restrict__ bw, const float* __restrict__ bb,
    const float* __restrict__ fcw, const float* __restrict__ fcb,
    const float* __restrict__ hw, const float* __restrict__ hb,
    float* __restrict__ fold) {
  int id = blockIdx.x*4 + (threadIdx.x >> 6);   // 0..851
  if (id >= 850) return;
  int row = id / 50, t = id % 50;
  int lane = threadIdx.x & 63;
  float acc = 0.f;
  for (int c = lane; c < COUT; c += 64) {
    float coef;
    if (row < NPTS) {
      coef = fcw[row*COUT + c];
    } else {
      int r = row - NPTS;
      coef = hw[(r >> 1)*(COUT*2) + c*2 + (r & 1)];
    }
    float wsum;
    if (t < KT) {
      const float* p = bw + c*(3*KT) + t;
      wsum = p[0] + p[KT] + p[2*KT];
    } else {
      wsum = bb[c];
    }
    acc += coef * wsum;
  }
  #pragma unroll
  for (int off = 32; off > 0; off >>= 1) acc += __shfl_down(acc, off);
  if (lane == 0) {
    if (t == KT) acc += (row < NPTS) ? fcb[row] : hb[row - NPTS];
    if (row < NPTS) {
      if (t < KT) fold[t*NPTS + row] = acc;                   // [t][k] layout
      else        fold[NPTS*KT + row] = acc;                  // scoreB at 539..549
    } else {
      int r = row - NPTS;
      if (t < KT) fold[550 + r*KT + t] = acc;                 // shiftW
      else        fold[844 + r] = acc;                        // shiftB
    }
  }
}

// ---------------------------------------------------------------------------
// Kernel 2 (R10): one block per (image, feature-cell k). The candidate rows
// of y-bucket k (rf = first, rl = last output row with y0-index k) need
// ONLY feature rows k and k+1 — so each block computes exactly those 2 rows
// x 128 cols x 11 ch (one conv pixel per thread, zero per-block redundancy;
// was 1.5 px/thread with 3x row redundancy in the row-split version), then
// evaluates its bucket's candidates.
// VERBATIM-preserved vs the absmax=0.0 kernels: per-pixel conv fmaf chain
// (branch-skip bounds), candidate column mapping (thread t -> x-bucket t>>1,
// first/last col), A/B/C/D row selection by bucket (B,D from row
// min(k+1,127) == LDS row 1), ty/y0i/wy float lines, reduce order, and the
// (val desc, idx asc) comparator. Partial count stays 128/point -> cascade
// byte-identical. Grid 1024 blocks (4/CU); XCD swizzle b=blk&7 keeps each
// image L2-resident on one XCD.
// R8 lesson kept: scalar stride-4 tap loads (wave-coalesced, L1-reused,
// 49 independent loads pipeline vs fmaf chains). Do NOT float4-ize.
__global__ __launch_bounds__(256) void score_argmax_kernel(
    const float* __restrict__ img, const float* __restrict__ fold,
    float* __restrict__ pval, int* __restrict__ pidx) {
  __shared__ __align__(16) float s[NPTS*2*FW];   // 11*2*128*4 = 11264 B
  __shared__ float wvv[NPTS*4];
  __shared__ int   wvi[NPTS*4];
  int b    = blockIdx.x & 7;     // image -> XCD (dispatch round-robins % 8)
  int cell = blockIdx.x >> 3;    // feature cell k: needs rows k, k+1
  const float* im = img + (size_t)b * (HH*WW);

  // --- conv phase: thread (ry=tid>>7, x=tid&127) computes pixel
  // (y=min(cell+ry,127), x) for all 11 channels. ry uniform per wave.
  // cell 127: both halves compute row 127 (harmless dup, matches y1 clamp).
  {
    int ry = threadIdx.x >> 7;               // 0 or 1
    int x  = threadIdx.x & 127;
    int y  = min(cell + ry, FH - 1);
    float acc[NPTS];
    #pragma unroll
    for (int k = 0; k < NPTS; ++k) acc[k] = fold[NPTS*KT + k];   // uniform -> s_load
    int iy0 = y*4 - 3, ix0 = x*4 - 3;
    #pragma unroll
    for (int kh = 0; kh < 7; ++kh) {
      int iy = iy0 + kh;
      if (iy < 0 || iy >= HH) continue;
      #pragma unroll
      for (int kw = 0; kw < 7; ++kw) {
        int ix = ix0 + kw;
        if (ix < 0 || ix >= WW) continue;
        float xv = im[iy*WW + ix] - 0.5f;
        int t = kh*7 + kw;
        #pragma unroll
        for (int k = 0; k < NPTS; ++k) acc[k] = fmaf(fold[t*NPTS + k], xv, acc[k]);
      }
    }
    #pragma unroll
    for (int k = 0; k < NPTS; ++k) s[(k*2 + ry)*FW + x] = acc[k];
  }
  __syncthreads();

  // --- argmax phase: candidates of bucket `cell` only ---
  // per-thread candidate column: thread t owns x-bucket t>>1, (t&1 ? last :
  // first) sampled col of that bucket. kb=127 is the singleton {511} (dup ok).
  int t = threadIdx.x;
  int kb = t >> 1;
  int cf = (kb*511 + 126)/127;
  int cl = (kb < 127) ? ((kb + 1)*511 + 126)/127 - 1 : 511;
  int ox = (t & 1) ? cl : cf;
  float tx = (float)ox * STEPC;
  int xa0 = (int)tx;
  float wx = tx - (float)xa0;
  int xa1 = min(xa0 + 1, FW - 1);
  float omwx = 1.f - wx;
  int wave = threadIdx.x >> 6;
  int lane = threadIdx.x & 63;

  int rf = (cell*511 + 126)/127;                                 // first row of bucket
  int rl = (cell < 127) ? ((cell + 1)*511 + 126)/127 - 1 : 511;  // last row

  #pragma unroll
  for (int ch = 0; ch < NPTS; ++ch) {
    float best = -3.4028235e38f;
    int bidx = 0x7fffffff;
    const float* r0 = s + (ch*2 + 0)*FW;     // feature row cell
    const float* r1 = s + (ch*2 + 1)*FW;     // feature row min(cell+1,127)
    float A = r0[xa0], B = r1[xa0], C = r0[xa1], D = r1[xa1];
    {
      float ty = (float)rf * STEPC;
      int y0i = (int)ty;
      float wy = ty - (float)y0i;
      float omwy = 1.f - wy;
      float top0 = A*omwy + B*wy;
      float top1 = C*omwy + D*wy;
      float v = top0*omwx + top1*wx;
      if (v > best) { best = v; bidx = rf*512 + ox; }
    }
    if (rl != rf) {
      float ty = (float)rl * STEPC;
      int y0i = (int)ty;
      float wy = ty - (float)y0i;
      float omwy = 1.f - wy;
      float top0 = A*omwy + B*wy;
      float top1 = C*omwy + D*wy;
      float v = top0*omwx + top1*wx;
      if (v > best) { best = v; bidx = rl*512 + ox; }
    }
    // intra-wave reduce (value desc, index asc tie-break) — no barriers
    #pragma unroll
    for (int off = 32; off > 0; off >>= 1) {
      float ov = __shfl_down(best, off);
      int   oi = __shfl_down(bidx, off);
      if (ov > best || (ov == best && oi < bidx)) { best = ov; bidx = oi; }
    }
    if (lane == 0) { wvv[ch*4 + wave] = best; wvi[ch*4 + wave] = bidx; }
  }
  __syncthreads();
  if (threadIdx.x < NPTS) {
    int ch = threadIdx.x;
    float best = wvv[ch*4]; int bidx = wvi[ch*4];
    #pragma unroll
    for (int w = 1; w < 4; ++w) {
      float ov = wvv[ch*4 + w]; int oi = wvi[ch*4 + w];
      if (ov > best || (ov == best && oi < bidx)) { best = ov; bidx = oi; }
    }
    int bk = b*NPTS + ch;
    pval[bk*NSPLIT + cell] = best;
    pidx[bk*NSPLIT + cell] = bidx;
  }
}

// ---------------------------------------------------------------------------
// Kernel 3 (R8, kept): one block per (b,k) point. Lane t<49 loads tap t in
// ONE parallel wave-load (was: lane-0-only serial loads = ~19 us exposed
// HBM latency on poison-flushed caches); all lanes replay the t=0..48
// serial fmaf chain via __shfl(xv,t) — OOB taps carry xv=0 and
// fmaf(w,0,acc)==acc (finite), so every chain intermediate equals the
// verbatim serial version. Merge comparator is an associative semilattice
// max -> wave-reduce gives the bit-identical winner.
__global__ __launch_bounds__(64) void cascade_kernel(
    const float* __restrict__ img, const float* __restrict__ fold,
    const float* __restrict__ pval, const int* __restrict__ pidx,
    float* __restrict__ out) {
  int p = blockIdx.x;          // bk index = b*11 + k
  int lane = threadIdx.x;      // 0..63
  float best = pval[p*NSPLIT + lane];
  int   bidx = pidx[p*NSPLIT + lane];
  {
    float v1 = pval[p*NSPLIT + 64 + lane];
    int   i1 = pidx[p*NSPLIT + 64 + lane];
    if (v1 > best || (v1 == best && i1 < bidx)) { best = v1; bidx = i1; }
  }
  #pragma unroll
  for (int off = 32; off > 0; off >>= 1) {
    float ov = __shfl_down(best, off);
    int   oi = __shfl_down(bidx, off);
    if (ov > best || (ov == best && oi < bidx)) { best = ov; bidx = oi; }
  }
  bidx = __shfl(bidx, 0);      // broadcast winner to all lanes

  float cx = (float)(bidx & 511);
  float cy = (float)(bidx >> 9);
  int b = p / NPTS;
  const float* im = img + (size_t)b * (HH*WW);
  int kh = lane / 7, kw = lane % 7;     // tap owned by this lane (lane<49)
  for (int i = 0; i < CASC; ++i) {
    // hi from y-coord, wi from x-coord; jnp.round = RNE = rintf
    float ry = rintf(cy * 0.25f), rx = rintf(cx * 0.25f);
    int hi = (int)fminf(fmaxf(ry, 0.f), (float)(FH - 1));
    int wi = (int)fminf(fmaxf(rx, 0.f), (float)(FW - 1));
    int iy0 = hi*4 - 3, ix0 = wi*4 - 3;
    float xv = 0.f;
    if (lane < KT) {
      int iy = iy0 + kh, ix = ix0 + kw;
      if (iy >= 0 && iy < HH && ix >= 0 && ix < WW)
        xv = im[iy*WW + ix] - 0.5f;
    }
    float s0 = fold[844 + i*2 + 0];
    float s1 = fold[844 + i*2 + 1];
    #pragma unroll
    for (int t = 0; t < KT; ++t) {
      float xvt = __shfl(xv, t);
      s0 = fmaf(fold[550 + (i*2 + 0)*KT + t], xvt, s0);
      s1 = fmaf(fold[550 + (i*2 + 1)*KT + t], xvt, s1);
    }
    cx += s0;     // uniform across lanes (same shfl data, same arithmetic)
    cy += s1;
  }
  if (lane == 0) {
    out[p*2 + 0] = cx;
    out[p*2 + 1] = cy;
  }
}

// ---------------------------------------------------------------------------
extern "C" void kernel_launch(void* const* d_in, const int* in_sizes, int n_in,
                              void* d_out, int out_size, void* d_ws, size_t ws_size,
                              hipStream_t stream) {
  const float* img = (const float*)d_in[0];   // (8,1,512,512)
  const float* bw  = (const float*)d_in[1];   // (256,3,7,7)
  const float* bb  = (const float*)d_in[2];   // (256,)
  const float* fcw = (const float*)d_in[3];   // (11,256)
  const float* fcb = (const float*)d_in[4];   // (11,)
  const float* hw  = (const float*)d_in[5];   // (3,256,2)
  const float* hb  = (const float*)d_in[6];   // (3,2)
  float* out = (float*)d_out;                 // (8,11,2) f32

  float* ws     = (float*)d_ws;
  float* fold   = ws + FOLD_OFF;
  float* pval   = ws + PVAL_OFF;
  int*   pidx   = (int*)(ws + PIDX_OFF);

  fold_kernel<<<213, 256, 0, stream>>>(bw, bb, fcw, fcb, hw, hb, fold);
  score_argmax_kernel<<<BATCH*NSPLIT, 256, 0, stream>>>(img, fold, pval, pidx);
  cascade_kernel<<<NBK, 64, 0, stream>>>(img, fold, pval, pidx, out);
}